// Round 17
// baseline (137.235 us; speedup 1.0000x reference)
//
#include <hip/hip_runtime.h>

// GCN forward: out = PReLU( D^-1/2 (A+I) D^-1/2 (x@W) + b )
//   xraw[i,:] = bf16( x[i,:] )
//   xa[i,:]   = bf16( di * ( sum_{s->i} ds*xraw[s] + di*xraw[i] ) ), d=rsqrt(deg+1)
//   out       = PReLU( xa @ W + b )
// R17 = R16 with k6 occupancy-fixed: LDS 64->48 KB (sB = 64-col Wt chunk,
// 16 KB) so 3 blocks/CU (768 co-resident slots ~ 782 blocks = 1.02 rounds,
// was 1.53 rounds at 2/CU -> ~24% tail hole). 8 B-chunks/block, same bytes.

typedef __attribute__((ext_vector_type(8))) short bf16x8_t;
typedef __attribute__((ext_vector_type(4))) float f32x4;

#define N_NODES 100000
#define N_EDGES 500000
#define K_IN    128
#define H_OUT   512
#define MAXDEG  32
#define NEB     1954     // ceil(N_EDGES/256) histogram blocks
#define NWB     256      // prepW blocks
#define NCB     12500    // conversion blocks (3.2M float4 / 256)
#define NMT     782      // ceil(N_NODES/128)

static __device__ __forceinline__ unsigned short f2b(float f) {
    unsigned u = __float_as_uint(f);
    u = (u + 0x7FFFu + ((u >> 16) & 1u)) >> 16;   // RNE
    return (unsigned short)u;
}
static __device__ __forceinline__ float b2lo(unsigned v) {
    return __uint_as_float(v << 16);
}
static __device__ __forceinline__ float b2hi(unsigned v) {
    return __uint_as_float(v & 0xFFFF0000u);
}

// K1: heterogeneous — deg histogram + inline padded-CSR fill | prepW | x->bf16
__global__ __launch_bounds__(256) void k1(const int* __restrict__ ei,
                                          int* __restrict__ deg,
                                          int* __restrict__ csrp,
                                          const float* __restrict__ W,
                                          unsigned short* __restrict__ Wt,
                                          const float* __restrict__ x,
                                          unsigned* __restrict__ xraw) {
    int b = blockIdx.x;
    if (b < NEB) {
        int e = b * 256 + threadIdx.x;
        if (e < N_EDGES) {
            int s = ei[e];
            int d = ei[N_EDGES + e];
            int r = atomicAdd(&deg[d], 1);
            csrp[d * MAXDEG + r] = s;
        }
    } else if (b < NEB + NWB) {
        int i = (b - NEB) * 256 + threadIdx.x;   // i = n*128+k
        int n = i >> 7, k = i & 127;
        Wt[i] = f2b(W[k * H_OUT + n]);
    } else {
        int t = (b - NEB - NWB) * 256 + threadIdx.x;   // 0 .. 3.2M-1 (exact)
        const float4* x4 = (const float4*)x;
        float4 xv = x4[t];
        unsigned p0 = ((unsigned)f2b(xv.y) << 16) | f2b(xv.x);
        unsigned p1 = ((unsigned)f2b(xv.w) << 16) | f2b(xv.z);
        *(uint2*)&xraw[2 * (size_t)t] = make_uint2(p0, p1);
    }
}

// K5: xa[i] = bf16( di*(sum_s ds*xraw[s] + di*xraw[i]) ), 1 wave/node.
// Adjacency as int4 pairs; unconditional clamped gathers; per-edge ds from
// broadcast deg[s] loads (L2-hot); tail masked via weight w=0.
__global__ __launch_bounds__(256) void k5(const unsigned* __restrict__ xraw,
                                          const int* __restrict__ csrp,
                                          const int* __restrict__ deg,
                                          unsigned* __restrict__ xa) {
    int wave = threadIdx.x >> 6, lane = threadIdx.x & 63;
    int node = blockIdx.x * 4 + wave;
    if (node >= N_NODES) return;

    unsigned sv = xraw[(size_t)node * 64 + lane];
    int cnt = __builtin_amdgcn_readfirstlane(deg[node]);
    float a0 = 0.f, a1 = 0.f;

    const int4* cp = (const int4*)(csrp + node * MAXDEG);
    for (int j = 0; j < cnt; j += 8) {
        int4 ca = cp[(j >> 2)];
        int4 cb = cp[(j >> 2) + 1];
        unsigned idx[8] = {(unsigned)ca.x, (unsigned)ca.y, (unsigned)ca.z, (unsigned)ca.w,
                           (unsigned)cb.x, (unsigned)cb.y, (unsigned)cb.z, (unsigned)cb.w};
        unsigned v[8];
        int dg[8];
        #pragma unroll
        for (int t = 0; t < 8; ++t) {
            unsigned id = idx[t] < N_NODES ? idx[t] : 0u;   // clamp poison pad
            v[t] = xraw[(size_t)id * 64 + lane];            // 256 B row gather
            dg[t] = deg[id];                                // broadcast, L2-hot
        }
        int rem = cnt - j;   // wave-uniform
        #pragma unroll
        for (int t = 0; t < 8; ++t) {
            float w = (t < rem) ? rsqrtf((float)(dg[t] + 1)) : 0.f;
            a0 += w * b2lo(v[t]);
            a1 += w * b2hi(v[t]);
        }
    }
    float di = rsqrtf((float)(cnt + 1));
    float f0 = di * (a0 + di * b2lo(sv));
    float f1 = di * (a1 + di * b2hi(sv));
    xa[(size_t)node * 64 + lane] = ((unsigned)f2b(f1) << 16) | f2b(f0);
}

// K6: A-resident GEMM, 48 KB LDS (3 blocks/CU). One block per 128-row
// m-tile (8 waves): stage swizzled xa tile once (32 KB); loop EIGHT 64-col
// Wt chunks (16 KB each); 2m x 4n wave grid, 4x1 frags; epilogue per chunk
// through ep (aliases sB), nontemporal f32x4 stores. Bijective XCD swizzle
// for NWG=782 (q=97, r=6).
__global__ __launch_bounds__(512) void k6(const unsigned short* __restrict__ xa,
                                          const unsigned short* __restrict__ Wt,
                                          const float* __restrict__ bias,
                                          const float* __restrict__ pw,
                                          float* __restrict__ out) {
    __shared__ char smem[49152];
    uint4* sA = (uint4*)smem;              // 32 KB: A tile, persists
    uint4* sB = (uint4*)(smem + 32768);    // 16 KB: 64-row Wt chunk
    float* ep = (float*)(smem + 32768);    // epilogue alias: 64 x 64 f32

    int orig = blockIdx.x;
    int xcd = orig & 7, loc = orig >> 3;
    int wgid = (xcd < 6 ? xcd * 98 : 588 + (xcd - 6) * 97) + loc;
    const int m0 = wgid * 128;
    const int tid = threadIdx.x;
    const int wave = tid >> 6, lane = tid & 63;

    const uint4* A4 = (const uint4*)xa;
    const uint4* B4 = (const uint4*)Wt;

    // stage A once (2048 uint4 / 512 threads = 4 each)
    #pragma unroll
    for (int r = 0; r < 4; ++r) {
        int i = tid + r * 512;
        int row = i >> 4, c = i & 15;
        int grow = m0 + row;
        uint4 o = (grow < N_NODES) ? A4[(size_t)grow * 16 + c]
                                   : make_uint4(0u, 0u, 0u, 0u);
        sA[row * 16 + (c ^ (row & 7))] = o;
    }

    const int wr = wave >> 2, wc = wave & 3;     // 2m x 4n wave grid
    const int l16 = lane & 15, lq = lane >> 4;

    for (int nc = 0; nc < 8; ++nc) {
        // stage B chunk: rows nc*64 .. +63 of Wt[512][128] (1024 uint4)
        #pragma unroll
        for (int r = 0; r < 2; ++r) {
            int i = tid + r * 512;
            int row = i >> 4, c = i & 15;
            sB[row * 16 + (c ^ (row & 7))] = B4[(size_t)(nc * 64 + row) * 16 + c];
        }
        __syncthreads();   // A (first iter) + B visible; prev ep reads done

        f32x4 acc[4];
        #pragma unroll
        for (int m = 0; m < 4; ++m)
            acc[m] = (f32x4){0.f, 0.f, 0.f, 0.f};

        #pragma unroll
        for (int kk = 0; kk < 4; ++kk) {
            bf16x8_t av[4], bv;
            #pragma unroll
            for (int m = 0; m < 4; ++m) {
                int row = wr * 64 + m * 16 + l16;
                av[m] = __builtin_bit_cast(bf16x8_t, sA[row * 16 + ((kk * 4 + lq) ^ (row & 7))]);
            }
            {
                int row = wc * 16 + l16;
                bv = __builtin_bit_cast(bf16x8_t, sB[row * 16 + ((kk * 4 + lq) ^ (row & 7))]);
            }
            #pragma unroll
            for (int m = 0; m < 4; ++m)
                acc[m] = __builtin_amdgcn_mfma_f32_16x16x32_bf16(av[m], bv, acc[m], 0, 0, 0);
        }
        __syncthreads();   // sB reads done before ep overwrites it

        int gn = nc * 64 + wc * 16 + l16;
        float bn = bias[gn], pn = pw[gn];

        // epilogue: 2 half-row phases (wr==h owns rows h*64 .. h*64+63)
        #pragma unroll
        for (int h = 0; h < 2; ++h) {
            if (wr == h) {
                #pragma unroll
                for (int m = 0; m < 4; ++m)
                    #pragma unroll
                    for (int r = 0; r < 4; ++r) {
                        int row = m * 16 + lq * 4 + r;   // 0..63 within half
                        float t = acc[m][r] + bn;
                        float v = t >= 0.f ? t : pn * t;
                        ep[row * 64 + wc * 16 + l16] = v;
                    }
            }
            __syncthreads();
            // read back: 16 threads/row (64 f32 = 16 f32x4), 32 rows/iter
            #pragma unroll
            for (int it = 0; it < 2; ++it) {
                int row = it * 32 + (tid >> 4);
                int gm = m0 + h * 64 + row;
                if (gm < N_NODES) {
                    int c4 = tid & 15;
                    f32x4 v = *(const f32x4*)&ep[row * 64 + c4 * 4];
                    __builtin_nontemporal_store(v, (f32x4*)&out[(size_t)gm * H_OUT + nc * 64 + c4 * 4]);
                }
            }
            __syncthreads();   // ep reads done before next phase / next chunk
        }
    }
}

extern "C" void kernel_launch(void* const* d_in, const int* in_sizes, int n_in,
                              void* d_out, int out_size, void* d_ws, size_t ws_size,
                              hipStream_t stream) {
    const float* x    = (const float*)d_in[0];
    const int*   ei   = (const int*)d_in[1];
    const float* W    = (const float*)d_in[2];
    const float* bias = (const float*)d_in[3];
    const float* pw   = (const float*)d_in[4];
    float* out = (float*)d_out;

    char* ws = (char*)d_ws;
    size_t off = 0;
    auto alloc = [&](size_t bytes) -> void* {
        void* p = ws + off;
        off += (bytes + 255) & ~(size_t)255;
        return p;
    };
    unsigned*       xraw = (unsigned*)alloc((size_t)N_NODES * K_IN * 2);       // 25.6 MB bf16
    unsigned*       xa   = (unsigned*)alloc((size_t)N_NODES * K_IN * 2);       // 25.6 MB bf16
    unsigned short* Wt   = (unsigned short*)alloc((size_t)K_IN * H_OUT * 2);   // 131 KB
    int*            deg  = (int*)alloc((size_t)N_NODES * 4);                   // 400 KB
    int*            csrp = (int*)alloc((size_t)N_NODES * MAXDEG * 4);          // 12.8 MB
    (void)ws_size; (void)in_sizes; (void)n_in; (void)out_size;

    hipMemsetAsync(deg, 0, (size_t)N_NODES * 4, stream);

    k1 <<<NEB + NWB + NCB, 256, 0, stream>>>(ei, deg, csrp, W, Wt, x, xraw);
    k5 <<<(N_NODES + 3) / 4, 256, 0, stream>>>(xraw, csrp, deg, xa);
    k6 <<<NMT, 512, 0, stream>>>((const unsigned short*)xa,
                                 (const unsigned short*)Wt, bias, pw, out);
}

// Round 18
// 127.518 us; speedup vs baseline: 1.0762x; 1.0762x over previous
//
#include <hip/hip_runtime.h>

// GCN forward: out = PReLU( D^-1/2 (A+I) D^-1/2 (x@W) + b )
// Aggregation commutes with the linear map:
//   xs[i,:] = bf16( dinv[i] * x[i,:] ),  dinv[i] = rsqrt(deg[i]+1)
//   xa[i,:] = bf16( dinv[i] * ( xs[i,:] + sum_{s->i} xs[s,:] ) )
//   out     = PReLU( xa @ W + b )
// R18 = exact revert to R13 (best measured: 126.1 us). R14-R17's mechanisms
// (fp8 payload, k2-fold, k6 48KB occupancy) all measured neutral/regressive.

typedef __attribute__((ext_vector_type(8))) short bf16x8_t;
typedef __attribute__((ext_vector_type(4))) float f32x4;

#define N_NODES 100000
#define N_EDGES 500000
#define K_IN    128
#define H_OUT   512
#define MAXDEG  32
#define NEB     1954     // ceil(N_EDGES/256)
#define NMT     782      // ceil(N_NODES/128)

static __device__ __forceinline__ unsigned short f2b(float f) {
    unsigned u = __float_as_uint(f);
    u = (u + 0x7FFFu + ((u >> 16) & 1u)) >> 16;   // RNE
    return (unsigned short)u;
}
static __device__ __forceinline__ float b2lo(unsigned v) {
    return __uint_as_float(v << 16);
}
static __device__ __forceinline__ float b2hi(unsigned v) {
    return __uint_as_float(v & 0xFFFF0000u);
}

// K1: deg histogram + INLINE padded-CSR fill (atomic old value = slot) | prepW
__global__ __launch_bounds__(256) void k1(const int* __restrict__ ei,
                                          int* __restrict__ deg,
                                          int* __restrict__ csrp,
                                          const float* __restrict__ W,
                                          unsigned short* __restrict__ Wt) {
    int b = blockIdx.x;
    if (b < NEB) {
        int e = b * 256 + threadIdx.x;
        if (e < N_EDGES) {
            int s = ei[e];
            int d = ei[N_EDGES + e];
            int r = atomicAdd(&deg[d], 1);
            csrp[d * MAXDEG + r] = s;
        }
    } else {
        int i = (b - NEB) * 256 + threadIdx.x;   // i = n*128+k
        int n = i >> 7, k = i & 127;
        Wt[i] = f2b(W[k * H_OUT + n]);
    }
}

// K2: xs[i] = bf16( rsqrt(deg+1) * x[i] ) — pure streaming.
__global__ __launch_bounds__(256) void k2(const int* __restrict__ deg,
                                          const float* __restrict__ x,
                                          unsigned* __restrict__ xs) {
    int i = blockIdx.x * 256 + threadIdx.x;      // 0 .. 6.4M-1
    int row = i >> 6;
    float d = rsqrtf((float)(deg[row] + 1));     // broadcast across wave
    const float2* x2 = (const float2*)x;
    float2 xv = x2[i];
    xs[i] = ((unsigned)f2b(d * xv.y) << 16) | f2b(d * xv.x);
}

// K5 (R11): 1 wave/node; adjacency as int4 pairs; unconditional clamped
// gathers, value-masked accumulate; plain xa store (keeps xa L2-resident).
__global__ __launch_bounds__(256) void k5(const unsigned* __restrict__ xs,
                                          const int* __restrict__ csrp,
                                          const int* __restrict__ deg,
                                          unsigned* __restrict__ xa) {
    int wave = threadIdx.x >> 6, lane = threadIdx.x & 63;
    int node = blockIdx.x * 4 + wave;
    if (node >= N_NODES) return;

    unsigned sv = xs[(size_t)node * 64 + lane];
    int cnt = __builtin_amdgcn_readfirstlane(deg[node]);
    float a0 = b2lo(sv), a1 = b2hi(sv);

    const int4* cp = (const int4*)(csrp + node * MAXDEG);
    for (int j = 0; j < cnt; j += 8) {
        int4 ca = cp[(j >> 2)];
        int4 cb = cp[(j >> 2) + 1];
        unsigned idx[8] = {(unsigned)ca.x, (unsigned)ca.y, (unsigned)ca.z, (unsigned)ca.w,
                           (unsigned)cb.x, (unsigned)cb.y, (unsigned)cb.z, (unsigned)cb.w};
        unsigned v[8];
        #pragma unroll
        for (int t = 0; t < 8; ++t) {
            unsigned id = idx[t] < N_NODES ? idx[t] : 0u;   // clamp poison pad
            v[t] = xs[(size_t)id * 64 + lane];
        }
        int rem = cnt - j;   // wave-uniform
        #pragma unroll
        for (int t = 0; t < 8; ++t) {
            unsigned val = (t < rem) ? v[t] : 0u;
            a0 += b2lo(val);
            a1 += b2hi(val);
        }
    }
    float di = rsqrtf((float)(cnt + 1));
    xa[(size_t)node * 64 + lane] = ((unsigned)f2b(di * a1) << 16) | f2b(di * a0);
}

// K6: A-resident GEMM. One block per 128-row m-tile (8 waves, 512 thr):
// stage swizzled xa tile once into sA; loop 4 n-chunks staging 128x128 Wt
// into sB; 2m x 4n wave grid, 4x2 frags; epilogue per chunk through ep
// (aliases sB) in 2 half-row phases, nontemporal f32x4 stores.
// Bijective XCD swizzle for NWG=782 (q=97, r=6).
__global__ __launch_bounds__(512) void k6(const unsigned short* __restrict__ xa,
                                          const unsigned short* __restrict__ Wt,
                                          const float* __restrict__ bias,
                                          const float* __restrict__ pw,
                                          float* __restrict__ out) {
    __shared__ char smem[65536];
    uint4* sA = (uint4*)smem;              // 32 KB: A tile, persists
    uint4* sB = (uint4*)(smem + 32768);    // 32 KB: Wt chunk
    float* ep = (float*)(smem + 32768);    // epilogue alias over sB: 64x128 f32

    int orig = blockIdx.x;
    int xcd = orig & 7, loc = orig >> 3;
    int wgid = (xcd < 6 ? xcd * 98 : 588 + (xcd - 6) * 97) + loc;
    const int m0 = wgid * 128;
    const int tid = threadIdx.x;
    const int wave = tid >> 6, lane = tid & 63;

    const uint4* A4 = (const uint4*)xa;
    const uint4* B4 = (const uint4*)Wt;

    // stage A once (2048 uint4 / 512 threads = 4 each)
    #pragma unroll
    for (int r = 0; r < 4; ++r) {
        int i = tid + r * 512;
        int row = i >> 4, c = i & 15;
        int grow = m0 + row;
        uint4 o = (grow < N_NODES) ? A4[(size_t)grow * 16 + c]
                                   : make_uint4(0u, 0u, 0u, 0u);
        sA[row * 16 + (c ^ (row & 7))] = o;
    }

    const int wr = wave >> 2, wc = wave & 3;     // 2m x 4n wave grid
    const int l16 = lane & 15, lq = lane >> 4;

    for (int nc = 0; nc < 4; ++nc) {
        // stage B chunk (rows nc*128 .. +127 of Wt[512][128])
        #pragma unroll
        for (int r = 0; r < 4; ++r) {
            int i = tid + r * 512;
            int row = i >> 4, c = i & 15;
            sB[row * 16 + (c ^ (row & 7))] = B4[(size_t)(nc * 128 + row) * 16 + c];
        }
        __syncthreads();   // A (first iter) + B visible

        f32x4 acc[4][2];
        #pragma unroll
        for (int m = 0; m < 4; ++m)
            #pragma unroll
            for (int n = 0; n < 2; ++n)
                acc[m][n] = (f32x4){0.f, 0.f, 0.f, 0.f};

        #pragma unroll
        for (int kk = 0; kk < 4; ++kk) {
            bf16x8_t av[4], bv[2];
            #pragma unroll
            for (int m = 0; m < 4; ++m) {
                int row = wr * 64 + m * 16 + l16;
                av[m] = __builtin_bit_cast(bf16x8_t, sA[row * 16 + ((kk * 4 + lq) ^ (row & 7))]);
            }
            #pragma unroll
            for (int n = 0; n < 2; ++n) {
                int row = wc * 32 + n * 16 + l16;
                bv[n] = __builtin_bit_cast(bf16x8_t, sB[row * 16 + ((kk * 4 + lq) ^ (row & 7))]);
            }
            #pragma unroll
            for (int m = 0; m < 4; ++m)
                #pragma unroll
                for (int n = 0; n < 2; ++n)
                    acc[m][n] = __builtin_amdgcn_mfma_f32_16x16x32_bf16(av[m], bv[n], acc[m][n], 0, 0, 0);
        }
        __syncthreads();   // sB reads done before ep overwrites it

        float bn[2], pn[2];
        #pragma unroll
        for (int n = 0; n < 2; ++n) {
            int gn = nc * 128 + wc * 32 + n * 16 + l16;
            bn[n] = bias[gn];
            pn[n] = pw[gn];
        }

        // epilogue: 2 half-row phases (wr==h writes rows h*64..h*64+63)
        #pragma unroll
        for (int h = 0; h < 2; ++h) {
            if (wr == h) {
                #pragma unroll
                for (int m = 0; m < 4; ++m)
                    #pragma unroll
                    for (int r = 0; r < 4; ++r) {
                        int row = m * 16 + lq * 4 + r;   // 0..63 within half
                        #pragma unroll
                        for (int n = 0; n < 2; ++n) {
                            float t = acc[m][n][r] + bn[n];
                            float v = t >= 0.f ? t : pn[n] * t;
                            ep[row * 128 + wc * 32 + n * 16 + l16] = v;
                        }
                    }
            }
            __syncthreads();
            // read back: 32 threads/row (128 f32 = 32 f32x4), 16 rows/iter
            #pragma unroll
            for (int it = 0; it < 4; ++it) {
                int row = it * 16 + (tid >> 5);
                int gm = m0 + h * 64 + row;
                if (gm < N_NODES) {
                    int c4 = tid & 31;
                    f32x4 v = *(const f32x4*)&ep[row * 128 + c4 * 4];
                    __builtin_nontemporal_store(v, (f32x4*)&out[(size_t)gm * H_OUT + nc * 128 + c4 * 4]);
                }
            }
            __syncthreads();   // ep reads done before next phase / next chunk
        }
    }
}

extern "C" void kernel_launch(void* const* d_in, const int* in_sizes, int n_in,
                              void* d_out, int out_size, void* d_ws, size_t ws_size,
                              hipStream_t stream) {
    const float* x    = (const float*)d_in[0];
    const int*   ei   = (const int*)d_in[1];
    const float* W    = (const float*)d_in[2];
    const float* bias = (const float*)d_in[3];
    const float* pw   = (const float*)d_in[4];
    float* out = (float*)d_out;

    char* ws = (char*)d_ws;
    size_t off = 0;
    auto alloc = [&](size_t bytes) -> void* {
        void* p = ws + off;
        off += (bytes + 255) & ~(size_t)255;
        return p;
    };
    unsigned*       xs   = (unsigned*)alloc((size_t)N_NODES * K_IN * 2);       // 25.6 MB
    unsigned*       xa   = (unsigned*)alloc((size_t)N_NODES * K_IN * 2);       // 25.6 MB
    unsigned short* Wt   = (unsigned short*)alloc((size_t)K_IN * H_OUT * 2);   // 131 KB
    int*            deg  = (int*)alloc((size_t)N_NODES * 4);                   // 400 KB
    int*            csrp = (int*)alloc((size_t)N_NODES * MAXDEG * 4);          // 12.8 MB
    (void)ws_size; (void)in_sizes; (void)n_in; (void)out_size;

    hipMemsetAsync(deg, 0, (size_t)N_NODES * 4, stream);

    k1 <<<NEB + 256, 256, 0, stream>>>(ei, deg, csrp, W, Wt);
    k2 <<<25000, 256, 0, stream>>>(deg, x, xs);
    k5 <<<(N_NODES + 3) / 4, 256, 0, stream>>>(xs, csrp, deg, xa);
    k6 <<<NMT, 512, 0, stream>>>((const unsigned short*)xa,
                                 (const unsigned short*)Wt, bias, pw, out);
}